// Round 5
// baseline (343.864 us; speedup 1.0000x reference)
//
#include <hip/hip_runtime.h>
#include <math.h>

namespace {

constexpr int B = 64;
constexpr int T = 4096;
constexpr int H = 1024;
constexpr float SCALE = 0.03125f;  // 1/sqrt(1024)
constexpr int WPB = 4;             // waves per block (256 threads)

typedef float v4f __attribute__((ext_vector_type(4)));

// Pass 1: single pass over enc_out with online softmax.
// TLP variant: depth-0 prefetch, <=64 VGPR so 8 waves/SIMD (32 waves/CU)
// are resident -- 2x the concurrent HBM streams of the depth-1 version.
// Each wave owns rpw contiguous rows; per row: 4 coalesced NT float4 loads,
// dot + 6-step shuffle reduce, online-softmax accumulate in registers.
__global__ __launch_bounds__(256, 8) void attn_pass1(
    const float* __restrict__ dec_h, const float* __restrict__ enc,
    float* __restrict__ scores, float* __restrict__ acc_ws,
    float* __restrict__ ml_ws, int chunks, int rpw) {
  const int b = blockIdx.y;
  const int wave = threadIdx.x >> 6;
  const int lane = threadIdx.x & 63;
  const int wslot = blockIdx.x * WPB + wave;  // [0, chunks*WPB)
  const int t0 = wslot * rpw;

  // dec fragment: this lane's 16 h-positions (4 strided groups of 4)
  const float* decb = dec_h + (size_t)b * H + lane * 4;
  const v4f d0 = *(const v4f*)(decb);
  const v4f d1 = *(const v4f*)(decb + 256);
  const v4f d2 = *(const v4f*)(decb + 512);
  const v4f d3 = *(const v4f*)(decb + 768);

  v4f a0 = {0.f, 0.f, 0.f, 0.f}, a1 = {0.f, 0.f, 0.f, 0.f};
  v4f a2 = {0.f, 0.f, 0.f, 0.f}, a3 = {0.f, 0.f, 0.f, 0.f};
  float m = -INFINITY;
  float l = 0.f;
  float sv = 0.f;

  // row pointer in v4f units; lane's slice at lane + k*64; row stride 256
  const v4f* rp = (const v4f*)(enc + ((size_t)b * T + t0) * H) + lane;
  float* srow = scores + (size_t)b * T + t0;

  for (int r = 0; r < rpw; ++r) {
    const v4f x0 = __builtin_nontemporal_load(rp);
    const v4f x1 = __builtin_nontemporal_load(rp + 64);
    const v4f x2 = __builtin_nontemporal_load(rp + 128);
    const v4f x3 = __builtin_nontemporal_load(rp + 192);
    rp += 256;

    // dot (two chains of fmas)
    float sA = x0[0] * d0[0] + x0[1] * d0[1] + x0[2] * d0[2] + x0[3] * d0[3];
    float sB = x1[0] * d1[0] + x1[1] * d1[1] + x1[2] * d1[2] + x1[3] * d1[3];
    sA += x2[0] * d2[0] + x2[1] * d2[1] + x2[2] * d2[2] + x2[3] * d2[3];
    sB += x3[0] * d3[0] + x3[1] * d3[1] + x3[2] * d3[2] + x3[3] * d3[3];
    float s = sA + sB;
#pragma unroll
    for (int off = 32; off > 0; off >>= 1) s += __shfl_xor(s, off, 64);
    s *= SCALE;

    // bank the wave-uniform score in lanes 0..31 (32-row period), then one
    // half-wave coalesced 128B store
    sv = (lane == (r & 31)) ? s : sv;
    if ((r & 31) == 31 && lane < 32) srow[(r & ~31) + lane] = sv;

    // online softmax (s is wave-uniform -> branch is non-divergent)
    if (s > m) {
      const float sc = __expf(m - s);  // m==-inf first time -> 0
      a0 *= sc; a1 *= sc; a2 *= sc; a3 *= sc;
      l *= sc;
      m = s;
    }
    const float p = __expf(s - m);
    l += p;
    a0 += p * x0;
    a1 += p * x1;
    a2 += p * x2;
    a3 += p * x3;
  }

  const size_t pi = (size_t)b * chunks * WPB + wslot;
  float* aw = acc_ws + pi * H + lane * 4;
  *(v4f*)(aw)       = a0;
  *(v4f*)(aw + 256) = a1;
  *(v4f*)(aw + 512) = a2;
  *(v4f*)(aw + 768) = a3;
  if (lane == 0) {
    ml_ws[2 * pi]     = m;
    ml_ws[2 * pi + 1] = l;
  }
}

// Pass 2: per batch, combine np partials -> ctx; normalize weights in place.
__global__ __launch_bounds__(256) void attn_pass2(
    const float* __restrict__ acc_ws, const float* __restrict__ ml_ws,
    float* __restrict__ ctx, float* __restrict__ weights, int np) {
  const int b = blockIdx.x;
  const int tid = threadIdx.x;
  const float* ml = ml_ws + 2 * (size_t)b * np;

  float M = -INFINITY;
  for (int i = 0; i < np; ++i) M = fmaxf(M, ml[2 * i]);
  float L = 0.f;
  for (int i = 0; i < np; ++i) L += ml[2 * i + 1] * __expf(ml[2 * i] - M);
  const float invL = 1.f / L;

  // ctx: 256 threads x 4 floats = 1024
  v4f a = {0.f, 0.f, 0.f, 0.f};
  const float* aw = acc_ws + (size_t)b * np * H + tid * 4;
  for (int i = 0; i < np; ++i) {
    const float w = __expf(ml[2 * i] - M);
    const v4f v = *(const v4f*)(aw + (size_t)i * H);
    a += w * v;
  }
  a *= invL;
  *(v4f*)(ctx + (size_t)b * H + tid * 4) = a;

  float* wrow = weights + (size_t)b * T;
  for (int t = tid; t < T; t += 256) {
    wrow[t] = __expf(wrow[t] - M) * invL;
  }
}

}  // namespace

extern "C" void kernel_launch(void* const* d_in, const int* in_sizes, int n_in,
                              void* d_out, int out_size, void* d_ws,
                              size_t ws_size, hipStream_t stream) {
  const float* dec_h = (const float*)d_in[0];
  const float* enc   = (const float*)d_in[1];
  float* ctx     = (float*)d_out;                  // [B,H]
  float* weights = (float*)d_out + (size_t)B * H;  // [B,T]

  // chunks=32 -> 8192 waves = 32 waves/CU (exact residency at <=64 VGPR).
  // Partial workspace need = B*chunks*WPB*(H+2)*4 bytes ~= 33.6 MB.
  int chunks = 32;
  while (chunks > 1 &&
         (size_t)B * chunks * WPB * (H + 2) * sizeof(float) > ws_size)
    chunks >>= 1;
  const int rpw = T / (chunks * WPB);  // 32 at chunks=32 (multiple of 32)
  const int np = chunks * WPB;

  float* acc_ws = (float*)d_ws;                 // [B*np][H]
  float* ml_ws  = acc_ws + (size_t)B * np * H;  // [B*np][2]

  dim3 g1(chunks, B);
  attn_pass1<<<g1, 256, 0, stream>>>(dec_h, enc, weights, acc_ws, ml_ws,
                                     chunks, rpw);
  attn_pass2<<<B, 256, 0, stream>>>(acc_ws, ml_ws, ctx, weights, np);
}

// Round 6
// 207.223 us; speedup vs baseline: 1.6594x; 1.6594x over previous
//
#include <hip/hip_runtime.h>
#include <math.h>

namespace {

constexpr int B = 64;
constexpr int T = 4096;
constexpr int H = 1024;
constexpr float SCALE = 0.03125f;  // 1/sqrt(1024)
constexpr int WPB = 4;             // waves per block (256 threads)

typedef float v4f __attribute__((ext_vector_type(4)));

// Pass 1: single pass over enc_out with online softmax.
// Each wave owns rpw contiguous rows of one batch. Depth-1 software
// pipeline: row r+1's loads are issued before row r's reduce chain so the
// wave always has ~4KB in flight. Scores are banked per-lane and stored
// coalesced once per 64 rows.
// NOTE (R4/R5 post-mortems): pair-ILP variant regressed (−2.5%) and the
// 64-VGPR/32-wave TLP variant spilled accumulators (−65%). This shape
// (~16 waves/CU, depth-1 prefetch, no launch_bounds min-wave pin) is the
// measured optimum: 208 µs, pass1 ~5.4 TB/s.
__global__ __launch_bounds__(256) void attn_pass1(
    const float* __restrict__ dec_h, const float* __restrict__ enc,
    float* __restrict__ scores, float* __restrict__ acc_ws,
    float* __restrict__ ml_ws, int chunks, int rpw) {
  const int b = blockIdx.y;
  const int wave = threadIdx.x >> 6;
  const int lane = threadIdx.x & 63;
  const int wslot = blockIdx.x * WPB + wave;  // [0, chunks*WPB)
  const int t0 = wslot * rpw;

  // dec fragment: this lane's 16 h-positions (4 strided groups of 4)
  const float* decb = dec_h + (size_t)b * H + lane * 4;
  const v4f d0 = *(const v4f*)(decb);
  const v4f d1 = *(const v4f*)(decb + 256);
  const v4f d2 = *(const v4f*)(decb + 512);
  const v4f d3 = *(const v4f*)(decb + 768);

  v4f a0 = {0.f, 0.f, 0.f, 0.f}, a1 = {0.f, 0.f, 0.f, 0.f};
  v4f a2 = {0.f, 0.f, 0.f, 0.f}, a3 = {0.f, 0.f, 0.f, 0.f};
  float m = -INFINITY;
  float l = 0.f;
  float sv = 0.f;

  // row pointer in v4f units; lane's slice at lane + k*64
  const v4f* rp = (const v4f*)(enc + ((size_t)b * T + t0) * H) + lane;
  float* srow = scores + (size_t)b * T + t0;

  v4f x0 = __builtin_nontemporal_load(rp);
  v4f x1 = __builtin_nontemporal_load(rp + 64);
  v4f x2 = __builtin_nontemporal_load(rp + 128);
  v4f x3 = __builtin_nontemporal_load(rp + 192);

  for (int r = 0; r < rpw; ++r) {
    v4f y0, y1, y2, y3;
    if (r + 1 < rpw) {
      const v4f* rq = rp + 256;
      y0 = __builtin_nontemporal_load(rq);
      y1 = __builtin_nontemporal_load(rq + 64);
      y2 = __builtin_nontemporal_load(rq + 128);
      y3 = __builtin_nontemporal_load(rq + 192);
    }
    rp += 256;

    // dot (two chains of fmas)
    float sA = x0[0] * d0[0] + x0[1] * d0[1] + x0[2] * d0[2] + x0[3] * d0[3];
    float sB = x1[0] * d1[0] + x1[1] * d1[1] + x1[2] * d1[2] + x1[3] * d1[3];
    sA += x2[0] * d2[0] + x2[1] * d2[1] + x2[2] * d2[2] + x2[3] * d2[3];
    sB += x3[0] * d3[0] + x3[1] * d3[1] + x3[2] * d3[2] + x3[3] * d3[3];
    float s = sA + sB;
#pragma unroll
    for (int off = 32; off > 0; off >>= 1) s += __shfl_xor(s, off, 64);
    s *= SCALE;

    // bank the wave-uniform score; one coalesced store per 64 rows
    sv = (lane == (r & 63)) ? s : sv;
    if ((r & 63) == 63) srow[(r & ~63) + lane] = sv;

    // online softmax (s is wave-uniform -> branch is non-divergent)
    if (s > m) {
      const float sc = __expf(m - s);  // m==-inf first time -> 0
      a0 *= sc; a1 *= sc; a2 *= sc; a3 *= sc;
      l *= sc;
      m = s;
    }
    const float p = __expf(s - m);
    l += p;
    a0 += p * x0;
    a1 += p * x1;
    a2 += p * x2;
    a3 += p * x3;

    x0 = y0; x1 = y1; x2 = y2; x3 = y3;
  }

  const size_t pi = (size_t)b * chunks * WPB + wslot;
  float* aw = acc_ws + pi * H + lane * 4;
  *(v4f*)(aw)       = a0;
  *(v4f*)(aw + 256) = a1;
  *(v4f*)(aw + 512) = a2;
  *(v4f*)(aw + 768) = a3;
  if (lane == 0) {
    ml_ws[2 * pi]     = m;
    ml_ws[2 * pi + 1] = l;
  }
}

// Pass 2: per batch, combine np partials -> ctx; normalize weights in place.
__global__ __launch_bounds__(256) void attn_pass2(
    const float* __restrict__ acc_ws, const float* __restrict__ ml_ws,
    float* __restrict__ ctx, float* __restrict__ weights, int np) {
  const int b = blockIdx.x;
  const int tid = threadIdx.x;
  const float* ml = ml_ws + 2 * (size_t)b * np;

  float M = -INFINITY;
  for (int i = 0; i < np; ++i) M = fmaxf(M, ml[2 * i]);
  float L = 0.f;
  for (int i = 0; i < np; ++i) L += ml[2 * i + 1] * __expf(ml[2 * i] - M);
  const float invL = 1.f / L;

  // ctx: 256 threads x 4 floats = 1024
  v4f a = {0.f, 0.f, 0.f, 0.f};
  const float* aw = acc_ws + (size_t)b * np * H + tid * 4;
  for (int i = 0; i < np; ++i) {
    const float w = __expf(ml[2 * i] - M);
    const v4f v = *(const v4f*)(aw + (size_t)i * H);
    a += w * v;
  }
  a *= invL;
  *(v4f*)(ctx + (size_t)b * H + tid * 4) = a;

  float* wrow = weights + (size_t)b * T;
  for (int t = tid; t < T; t += 256) {
    wrow[t] = __expf(wrow[t] - M) * invL;
  }
}

}  // namespace

extern "C" void kernel_launch(void* const* d_in, const int* in_sizes, int n_in,
                              void* d_out, int out_size, void* d_ws,
                              size_t ws_size, hipStream_t stream) {
  const float* dec_h = (const float*)d_in[0];
  const float* enc   = (const float*)d_in[1];
  float* ctx     = (float*)d_out;                  // [B,H]
  float* weights = (float*)d_out + (size_t)B * H;  // [B,T]

  // Largest chunk count whose partial workspace fits in d_ws.
  // need = B*chunks*WPB*(H+2)*4 bytes ~= chunks * 1.05 MB
  int chunks = 16;
  while (chunks > 1 &&
         (size_t)B * chunks * WPB * (H + 2) * sizeof(float) > ws_size)
    chunks >>= 1;
  const int rpw = T / (chunks * WPB);  // 64 at chunks=16 (even, mult of 64)
  const int np = chunks * WPB;

  float* acc_ws = (float*)d_ws;                 // [B*np][H]
  float* ml_ws  = acc_ws + (size_t)B * np * H;  // [B*np][2]

  dim3 g1(chunks, B);
  attn_pass1<<<g1, 256, 0, stream>>>(dec_h, enc, weights, acc_ws, ml_ws,
                                     chunks, rpw);
  attn_pass2<<<B, 256, 0, stream>>>(acc_ws, ml_ws, ctx, weights, np);
}